// Round 1
// 1610.544 us; speedup vs baseline: 2.6334x; 2.6334x over previous
//
#include <hip/hip_runtime.h>
#include <cmath>

// Scattering transform, two orders. B=32, C=3, P=8, 512x512 in, 7x7 filters, pad 3.
// Per input channel gq (filter bank index gq%3):
//   - phi conv stride 2            -> out channel gq
//   - 8x (psi_r,psi_i) conv stride 2, modulus, phi-smooth stride 1
//                                  -> out channels Cin + gq*8 + j
// Stage 1: in = x   [32][ 3][512][512] -> s1  [32][ 27][256][256] (workspace)
// Stage 2: in = s1  [32][27][256][256] -> out [32][243][128][128]
//
// R1 restructure: tap-OUTER band-pass loop. Each thread owns 6 positions x 8
// accumulators; the 8 packed weights are s_loaded ONCE per tap (not once per
// position-iteration). Rationale: scalar loads complete out-of-order on CDNA,
// so every weight use costs a full `s_waitcnt lgkmcnt(0)` that also drains all
// in-flight ds_reads. Old structure paid that drain every 8 FMAs; new one pays
// it every 48 FMAs and lets ds_reads pipeline. Smoothing/phi convs switched to
// 4-row column register tiles (70 LDS reads / 4 outputs instead of 196).

#define TILE 32
#define UH   38   // TILE + 6 (3-px halo each side for the smoothing conv)
#define US   39   // padded LDS row stride for u tiles
#define XT   81   // 2*TILE + 17 input rows/cols needed per tile

__global__ void pack_weights_kernel(const float* __restrict__ psi_r,
                                    const float* __restrict__ psi_i,
                                    float* __restrict__ wpack) {
  // wpack layout: [g=3][tap=49][j=8][{r,i}=2]  (16 consecutive floats per tap)
  int idx = blockIdx.x * 256 + threadIdx.x;
  if (idx >= 3 * 49 * 8) return;
  int j   = idx % 8;
  int tap = (idx / 8) % 49;
  int g   = idx / (8 * 49);
  int src = (g * 8 + j) * 49 + tap;
  wpack[idx * 2 + 0] = psi_r[src];
  wpack[idx * 2 + 1] = psi_i[src];
}

__global__ __launch_bounds__(256) void scatter_stage_kernel(
    const float* __restrict__ in,     // [B][Cin][Hin][Win]
    const float* __restrict__ phi,    // [3][49]
    const float* __restrict__ wpack,  // [3][49][8][2]
    float* __restrict__ out,          // [B][Cin*9][Hin/2][Win/2]
    int Cin, int Hin, int Win, int tilesX)
{
  const int Hout = Hin >> 1, Wout = Win >> 1;
  const int gq  = blockIdx.y;
  const int b   = blockIdx.z;
  const int ty0 = (blockIdx.x / tilesX) * TILE;
  const int tx0 = (blockIdx.x % tilesX) * TILE;
  const int g3  = gq % 3;
  const int tid = threadIdx.x;

  __shared__ float xs[XT][XT];      // 26244 B
  __shared__ float us[4][UH][US];   // 23712 B  (total ~50 KB -> 3 blocks/CU)
  const float* __restrict__ xsf = &xs[0][0];

  const float* __restrict__ inp =
      in + ((size_t)b * Cin + gq) * ((size_t)Hin * Win);
  float* __restrict__ outp =
      out + (size_t)b * (size_t)(Cin * 9) * (size_t)(Hout * Wout);

  // ---- load input tile (zero-padded) ----
  const int iy0 = 2 * ty0 - 9;   // = 2*(ty0-3) - 3
  const int ix0 = 2 * tx0 - 9;
  for (int i = tid; i < XT * XT; i += 256) {
    int r = i / XT, c = i - r * XT;
    int gy = iy0 + r, gx = ix0 + c;
    float v = 0.0f;
    if ((unsigned)gy < (unsigned)Hin && (unsigned)gx < (unsigned)Win)
      v = inp[(size_t)gy * Win + gx];
    xs[r][c] = v;
  }
  __syncthreads();

  const int ox  = tid & 31;          // column-tile mapping for phi/smooth convs
  const int oy0 = (tid >> 5) << 2;   // 8 groups x 4 consecutive rows = 32 rows

  // ---- phi low-pass, stride 2 -> out channel gq (4-row register column) ----
  {
    const float* __restrict__ wph = phi + g3 * 49;
    float a0 = 0.f, a1 = 0.f, a2 = 0.f, a3 = 0.f;
    #pragma unroll
    for (int kx = 0; kx < 7; kx++) {
      float v[13];
      #pragma unroll
      for (int r = 0; r < 13; r++)
        v[r] = xs[2 * oy0 + r + 6][2 * ox + kx + 6];
      #pragma unroll
      for (int ky = 0; ky < 7; ky++) {
        float w = wph[ky * 7 + kx];
        a0 = fmaf(v[ky + 0], w, a0);
        a1 = fmaf(v[ky + 2], w, a1);
        a2 = fmaf(v[ky + 4], w, a2);
        a3 = fmaf(v[ky + 6], w, a3);
      }
    }
    size_t o = ((size_t)gq * Hout + (ty0 + oy0)) * Wout + (tx0 + ox);
    outp[o]            = a0;
    outp[o + Wout]     = a1;
    outp[o + 2 * Wout] = a2;
    outp[o + 3 * Wout] = a3;
  }

  // ---- band-pass modulus + smoothing, 4 psi filter pairs per half ----
  #pragma unroll 1
  for (int half = 0; half < 2; half++) {
    __syncthreads();   // protect us[] reuse across halves

    // 6 positions per thread (1444 positions; overflow threads recompute the
    // last position -> duplicate identical us write, benign)
    int lb[6], puy[6], pux[6];
    float aR[6][4], aI[6][4];
    #pragma unroll
    for (int p = 0; p < 6; p++) {
      int i = tid + p * 256;
      if (i > UH * UH - 1) i = UH * UH - 1;
      int uy = i / UH, ux = i - uy * UH;
      puy[p] = uy; pux[p] = ux;
      lb[p] = (2 * uy) * XT + 2 * ux;
      #pragma unroll
      for (int q = 0; q < 4; q++) { aR[p][q] = 0.f; aI[p][q] = 0.f; }
    }

    const float* __restrict__ wt = wpack + g3 * (49 * 16) + half * 8;
    #pragma unroll 1
    for (int ky = 0; ky < 7; ky++) {
      const float* __restrict__ wrow = wt + ky * 7 * 16;
      #pragma unroll
      for (int kx = 0; kx < 7; kx++) {
        // 8 wave-uniform weights, one scalar fetch per tap for 48 FMAs
        const float* __restrict__ w = wrow + kx * 16;
        float w0 = w[0], w1 = w[1], w2 = w[2], w3 = w[3];
        float w4 = w[4], w5 = w[5], w6 = w[6], w7 = w[7];
        #pragma unroll
        for (int p = 0; p < 6; p++) {
          float xv = xsf[lb[p] + ky * XT + kx];
          aR[p][0] = fmaf(xv, w0, aR[p][0]); aI[p][0] = fmaf(xv, w1, aI[p][0]);
          aR[p][1] = fmaf(xv, w2, aR[p][1]); aI[p][1] = fmaf(xv, w3, aI[p][1]);
          aR[p][2] = fmaf(xv, w4, aR[p][2]); aI[p][2] = fmaf(xv, w5, aI[p][2]);
          aR[p][3] = fmaf(xv, w6, aR[p][3]); aI[p][3] = fmaf(xv, w7, aI[p][3]);
        }
      }
    }

    #pragma unroll
    for (int p = 0; p < 6; p++) {
      int uy = puy[p], ux = pux[p];
      int uyg = ty0 - 3 + uy, uxg = tx0 - 3 + ux;
      // positions outside the valid stride-2 grid contribute zero (conv padding)
      bool valid = ((unsigned)uyg < (unsigned)Hout) & ((unsigned)uxg < (unsigned)Wout);
      #pragma unroll
      for (int q = 0; q < 4; q++) {
        float m = sqrtf(aR[p][q] * aR[p][q] + aI[p][q] * aI[p][q]);
        us[q][uy][ux] = valid ? m : 0.0f;
      }
    }
    __syncthreads();

    // ---- smoothing: 4-row register column per thread, 70 LDS reads / 4 outs ----
    for (int j4 = 0; j4 < 4; j4++) {
      const int j  = half * 4 + j4;
      const int pf = (gq * 8 + j) % 3;     // tiled-phi filter index
      const float* __restrict__ wsm = phi + pf * 49;
      const int ch = Cin + gq * 8 + j;
      float a0 = 0.f, a1 = 0.f, a2 = 0.f, a3 = 0.f;
      #pragma unroll
      for (int kx = 0; kx < 7; kx++) {
        float v[10];
        #pragma unroll
        for (int r = 0; r < 10; r++)
          v[r] = us[j4][oy0 + r][ox + kx];
        #pragma unroll
        for (int ky = 0; ky < 7; ky++) {
          float w = wsm[ky * 7 + kx];
          a0 = fmaf(v[ky + 0], w, a0);
          a1 = fmaf(v[ky + 1], w, a1);
          a2 = fmaf(v[ky + 2], w, a2);
          a3 = fmaf(v[ky + 3], w, a3);
        }
      }
      size_t o = ((size_t)ch * Hout + (ty0 + oy0)) * Wout + (tx0 + ox);
      outp[o]            = a0;
      outp[o + Wout]     = a1;
      outp[o + 2 * Wout] = a2;
      outp[o + 3 * Wout] = a3;
    }
  }
}

extern "C" void kernel_launch(void* const* d_in, const int* in_sizes, int n_in,
                              void* d_out, int out_size, void* d_ws, size_t ws_size,
                              hipStream_t stream) {
  const float* x     = (const float*)d_in[0];  // [32][3][512][512]
  const float* phi   = (const float*)d_in[1];  // [3][1][7][7]
  const float* psi_r = (const float*)d_in[2];  // [24][1][7][7]
  const float* psi_i = (const float*)d_in[3];  // [24][1][7][7]
  float* out = (float*)d_out;                  // [32][243][128][128]

  float* s1    = (float*)d_ws;                           // [32][27][256][256] = 226.5 MB
  float* wpack = s1 + (size_t)32 * 27 * 256 * 256;       // 2352 floats

  pack_weights_kernel<<<dim3(5), 256, 0, stream>>>(psi_r, psi_i, wpack);

  // Stage 1: x -> s1   (Cin=3, 512x512 -> 256x256; 8x8 tiles)
  scatter_stage_kernel<<<dim3(64, 3, 32), 256, 0, stream>>>(
      x, phi, wpack, s1, 3, 512, 512, 8);

  // Stage 2: s1 -> out (Cin=27, 256x256 -> 128x128; 4x4 tiles)
  scatter_stage_kernel<<<dim3(16, 27, 32), 256, 0, stream>>>(
      s1, phi, wpack, out, 27, 256, 256, 4);
}

// Round 2
// 1497.128 us; speedup vs baseline: 2.8329x; 1.0758x over previous
//
#include <hip/hip_runtime.h>
#include <cmath>

// Scattering transform, two orders. B=32, C=3, P=8, 512x512 in, 7x7 filters, pad 3.
// Per input channel gq (filter bank index gq%3):
//   - phi conv stride 2            -> out channel gq
//   - 8x (psi_r,psi_i) conv stride 2, modulus, phi-smooth stride 1
//                                  -> out channels Cin + gq*8 + j
// Stage 1: in = x   [32][ 3][512][512] -> s1  [32][ 27][256][256] (workspace)
// Stage 2: in = s1  [32][27][256][256] -> out [32][243][128][128]
//
// R2 restructure: the kernel was LDS-pipe bound (1313 ds ops/thread, 4-way bank
// conflicts from stride-2 column reads => ~830us of LDS time vs 290us FMA floor).
//   (a) xs stored split by column parity (xs2[2][81][41]): stride-2 reads become
//       stride-1 within one parity plane -> conflict-free; plane = kx&1 (uniform).
//   (b) band-pass: thread owns a COLUMN of 7 u-positions; per kx load 19 column
//       values once, reuse over 7ky x 7pos  (133 reads/half vs 294).
//   (c) smoothing: one wave per psi filter, 16-tall column per thread
//       (154 reads/half vs 280). Filter weights made scalar via readfirstlane.

#define TILE 32
#define UH   38   // TILE + 6 (3-px halo each side for the smoothing conv)
#define US   39   // padded LDS row stride for u tiles
#define XT   81   // 2*TILE + 17 input rows/cols needed per tile
#define XES  41   // column count per parity plane (even cols 0..80 -> 41)

__global__ void pack_weights_kernel(const float* __restrict__ psi_r,
                                    const float* __restrict__ psi_i,
                                    float* __restrict__ wpack) {
  // wpack layout: [g=3][tap=49][j=8][{r,i}=2]  (16 consecutive floats per tap)
  int idx = blockIdx.x * 256 + threadIdx.x;
  if (idx >= 3 * 49 * 8) return;
  int j   = idx % 8;
  int tap = (idx / 8) % 49;
  int g   = idx / (8 * 49);
  int src = (g * 8 + j) * 49 + tap;
  wpack[idx * 2 + 0] = psi_r[src];
  wpack[idx * 2 + 1] = psi_i[src];
}

__global__ __launch_bounds__(256) void scatter_stage_kernel(
    const float* __restrict__ in,     // [B][Cin][Hin][Win]
    const float* __restrict__ phi,    // [3][49]
    const float* __restrict__ wpack,  // [3][49][8][2]
    float* __restrict__ out,          // [B][Cin*9][Hin/2][Win/2]
    int Cin, int Hin, int Win, int tilesX)
{
  const int Hout = Hin >> 1, Wout = Win >> 1;
  const int gq  = blockIdx.y;
  const int b   = blockIdx.z;
  const int ty0 = (blockIdx.x / tilesX) * TILE;
  const int tx0 = (blockIdx.x % tilesX) * TILE;
  const int g3  = gq % 3;
  const int tid = threadIdx.x;

  __shared__ float xs2[2][XT][XES];  // 26568 B  (even cols plane, odd cols plane)
  __shared__ float us[4][UH][US];    // 23712 B  (total ~50.3 KB -> 3 blocks/CU)

  const float* __restrict__ inp =
      in + ((size_t)b * Cin + gq) * ((size_t)Hin * Win);
  float* __restrict__ outp =
      out + (size_t)b * (size_t)(Cin * 9) * (size_t)(Hout * Wout);

  // ---- load input tile (zero-padded), split by column parity ----
  const int iy0 = 2 * ty0 - 9;   // = 2*(ty0-3) - 3
  const int ix0 = 2 * tx0 - 9;
  for (int i = tid; i < XT * XT; i += 256) {
    int r = i / XT, c = i - r * XT;
    int gy = iy0 + r, gx = ix0 + c;
    float v = 0.0f;
    if ((unsigned)gy < (unsigned)Hin && (unsigned)gx < (unsigned)Win)
      v = inp[(size_t)gy * Win + gx];
    xs2[c & 1][r][c >> 1] = v;
  }
  __syncthreads();

  const int ox  = tid & 31;          // column-tile mapping for the phi conv
  const int oy0 = (tid >> 5) << 2;   // 8 groups x 4 consecutive rows

  // ---- phi low-pass, stride 2 -> out channel gq (4-row register column) ----
  {
    const float* __restrict__ wph = phi + g3 * 49;
    float a0 = 0.f, a1 = 0.f, a2 = 0.f, a3 = 0.f;
    #pragma unroll
    for (int kx = 0; kx < 7; kx++) {
      // column 2*ox + kx + 6 lives in plane kx&1 at index ox + ((kx+6)>>1)
      const float* __restrict__ col = &xs2[kx & 1][0][ox + ((kx + 6) >> 1)];
      float v[13];
      #pragma unroll
      for (int r = 0; r < 13; r++)
        v[r] = col[(2 * oy0 + r + 6) * XES];
      #pragma unroll
      for (int ky = 0; ky < 7; ky++) {
        float w = wph[ky * 7 + kx];
        a0 = fmaf(v[ky + 0], w, a0);
        a1 = fmaf(v[ky + 2], w, a1);
        a2 = fmaf(v[ky + 4], w, a2);
        a3 = fmaf(v[ky + 6], w, a3);
      }
    }
    size_t o = ((size_t)gq * Hout + (ty0 + oy0)) * Wout + (tx0 + ox);
    outp[o]            = a0;
    outp[o + Wout]     = a1;
    outp[o + 2 * Wout] = a2;
    outp[o + 3 * Wout] = a3;
  }

  // ---- band-pass position mapping: thread owns a column of 7 u-rows ----
  // 38 cols x 6 row-groups (0,7,14,21,28,31); groups 5/6 overlap -> benign
  // duplicate writes of identical values. All 38x38 positions covered.
  const int g6   = tid / 38;
  const int bux  = tid - g6 * 38;        // u column 0..37
  int buy0 = 7 * g6; if (buy0 > 31) buy0 = 31;

  // smoothing mapping: one wave per filter, 16-tall column per thread
  const int sq  = tid >> 6;              // wave id = filter j4
  const int sox = tid & 31;
  const int sry = ((tid >> 5) & 1) << 4; // 0 or 16

  #pragma unroll 1
  for (int half = 0; half < 2; half++) {
    __syncthreads();   // us[] reuse across halves

    float aR[7][4], aI[7][4];
    #pragma unroll
    for (int p = 0; p < 7; p++)
      #pragma unroll
      for (int q = 0; q < 4; q++) { aR[p][q] = 0.f; aI[p][q] = 0.f; }

    const float* __restrict__ wt = wpack + g3 * (49 * 16) + half * 8;
    #pragma unroll 1
    for (int kx = 0; kx < 7; kx++) {
      // column 2*bux + kx lives in plane kx&1 at index bux + (kx>>1)
      const float* __restrict__ colp = &xs2[kx & 1][0][bux + (kx >> 1)];
      float v[19];
      #pragma unroll
      for (int rr = 0; rr < 19; rr++)
        v[rr] = colp[(2 * buy0 + rr) * XES];
      #pragma unroll
      for (int ky = 0; ky < 7; ky++) {
        const float* __restrict__ w = wt + (ky * 7 + kx) * 16;
        float w0 = w[0], w1 = w[1], w2 = w[2], w3 = w[3];
        float w4 = w[4], w5 = w[5], w6 = w[6], w7 = w[7];
        #pragma unroll
        for (int p = 0; p < 7; p++) {
          float xv = v[2 * p + ky];
          aR[p][0] = fmaf(xv, w0, aR[p][0]); aI[p][0] = fmaf(xv, w1, aI[p][0]);
          aR[p][1] = fmaf(xv, w2, aR[p][1]); aI[p][1] = fmaf(xv, w3, aI[p][1]);
          aR[p][2] = fmaf(xv, w4, aR[p][2]); aI[p][2] = fmaf(xv, w5, aI[p][2]);
          aR[p][3] = fmaf(xv, w6, aR[p][3]); aI[p][3] = fmaf(xv, w7, aI[p][3]);
        }
      }
    }

    #pragma unroll
    for (int p = 0; p < 7; p++) {
      int uy  = buy0 + p;                       // <= 37 always
      int uyg = ty0 - 3 + uy, uxg = tx0 - 3 + bux;
      // positions outside the valid stride-2 grid contribute zero (conv padding)
      bool valid = ((unsigned)uyg < (unsigned)Hout) & ((unsigned)uxg < (unsigned)Wout);
      #pragma unroll
      for (int q = 0; q < 4; q++) {
        float m = sqrtf(aR[p][q] * aR[p][q] + aI[p][q] * aI[p][q]);
        us[q][uy][bux] = valid ? m : 0.0f;
      }
    }
    __syncthreads();

    // ---- smoothing: wave sq handles filter j = half*4+sq, 16-row column ----
    {
      const int j  = half * 4 + sq;
      int pf = (gq * 8 + j) % 3;               // tiled-phi filter index
      pf = __builtin_amdgcn_readfirstlane(pf); // wave-uniform -> scalar loads
      const float* __restrict__ wsm = phi + pf * 49;
      const int ch = Cin + gq * 8 + j;
      float acc[16];
      #pragma unroll
      for (int p = 0; p < 16; p++) acc[p] = 0.f;
      #pragma unroll 1
      for (int kx = 0; kx < 7; kx++) {
        float v[22];
        #pragma unroll
        for (int rr = 0; rr < 22; rr++)
          v[rr] = us[sq][sry + rr][sox + kx];
        #pragma unroll
        for (int ky = 0; ky < 7; ky++) {
          float w = wsm[ky * 7 + kx];
          #pragma unroll
          for (int p = 0; p < 16; p++)
            acc[p] = fmaf(v[p + ky], w, acc[p]);
        }
      }
      size_t o = ((size_t)ch * Hout + (ty0 + sry)) * Wout + (tx0 + sox);
      #pragma unroll
      for (int p = 0; p < 16; p++)
        outp[o + (size_t)p * Wout] = acc[p];
    }
  }
}

extern "C" void kernel_launch(void* const* d_in, const int* in_sizes, int n_in,
                              void* d_out, int out_size, void* d_ws, size_t ws_size,
                              hipStream_t stream) {
  const float* x     = (const float*)d_in[0];  // [32][3][512][512]
  const float* phi   = (const float*)d_in[1];  // [3][1][7][7]
  const float* psi_r = (const float*)d_in[2];  // [24][1][7][7]
  const float* psi_i = (const float*)d_in[3];  // [24][1][7][7]
  float* out = (float*)d_out;                  // [32][243][128][128]

  float* s1    = (float*)d_ws;                           // [32][27][256][256] = 226.5 MB
  float* wpack = s1 + (size_t)32 * 27 * 256 * 256;       // 2352 floats

  pack_weights_kernel<<<dim3(5), 256, 0, stream>>>(psi_r, psi_i, wpack);

  // Stage 1: x -> s1   (Cin=3, 512x512 -> 256x256; 8x8 tiles)
  scatter_stage_kernel<<<dim3(64, 3, 32), 256, 0, stream>>>(
      x, phi, wpack, s1, 3, 512, 512, 8);

  // Stage 2: s1 -> out (Cin=27, 256x256 -> 128x128; 4x4 tiles)
  scatter_stage_kernel<<<dim3(16, 27, 32), 256, 0, stream>>>(
      s1, phi, wpack, out, 27, 256, 256, 4);
}